// Round 2
// baseline (219.069 us; speedup 1.0000x reference)
//
#include <hip/hip_runtime.h>
#include <hip/hip_bf16.h>

// Conv2D 3x3 pad1 stride1: x(32,32,128,128) fp32 * w(64,32,3,3) + bias -> (32,64,128,128) fp32
// bf16 MFMA implicit GEMM.
// Round 5: 8-output-row blocks (512 blocks = exactly 2/CU), rolling 6-row LDS
// ring, 4 compute steps of 2 rows each. Halo read factor 1.25x (was 1.5x).
// MFMA operands SWAPPED vs R4: x is the A operand (M=w), weights are B (N=ok).
// D-layout then gives each lane 4 consecutive w per fragment -> float4 output
// stores (8 dwordx4 per wave-step instead of 32 dword), bias hoisted.
// Prefetch for step s+1 issued at the top of step s's compute so HBM latency
// (~900cy) hides under the MFMA phase (~1400cy); LDS write lands just before
// the barrier that publishes it.

typedef __attribute__((ext_vector_type(8))) short bf16x8;
typedef __attribute__((ext_vector_type(4))) float f32x4;

#define NB 32
#define CIN 32
#define HH 128
#define WW 128
#define NK 64
#define XROW (130 * 32)   // one LDS x row: wi 0..129 (w halo), c 0..31

__device__ __forceinline__ unsigned short f2bf(float f) {
    union { float f; unsigned int u; } v; v.f = f;
    unsigned int u = v.u;
    return (unsigned short)((u + 0x7FFFu + ((u >> 16) & 1u)) >> 16);  // RNE
}

// LDS x element: [wi][c] bf16, 16B-chunk XOR swizzle spreads banks for the
// b32 transpose writes and keeps b128 frag reads uniform.
__device__ __forceinline__ int xel(int wi, int c) {
    return wi * 32 + ((((c >> 3) ^ ((wi >> 2) & 3)) << 3) | (c & 7));
}

// Pre-kernel: kern[ok][c*9+kidx] fp32 -> wfrag bf16 in fragment order:
// wfrag[((kidx*4 + tile)*64 + lane)*8 + j], ok = tile*16 + (lane&15), c = (lane>>4)*8 + j.
// Same per-lane layout serves as A-frag (R4) or B-frag (R5 swapped) since
// A/B lane maps are mirrored (own-dim = lane&15, k = (lane>>4)*8+j).
__global__ void repack_w(const float* __restrict__ kern,
                         unsigned short* __restrict__ wfrag) {
    int u = blockIdx.x * 256 + threadIdx.x;      // 0..18431
    int j = u & 7;
    int lane = (u >> 3) & 63;
    int tile = (u >> 9) & 3;
    int kidx = u >> 11;
    int ok = tile * 16 + (lane & 15);
    int c = ((lane >> 4) << 3) + j;
    wfrag[u] = f2bf(kern[ok * 288 + c * 9 + kidx]);
}

__global__ __launch_bounds__(512, 4) void conv3x3_mfma(
        const float* __restrict__ x, const unsigned short* __restrict__ wfrag,
        const float* __restrict__ bias, float* __restrict__ out) {
    __shared__ unsigned short lds_x[6 * XROW];   // 49920 B

    const int tid = threadIdx.x;
    const int bx = blockIdx.x;                   // 0..15 (h octets)
    // XCD swizzle: XCD i gets hgroups 2i,2i+1 -> rows 16i..16i+15; adjacent
    // hgroups (sharing boundary x rows) hit the same XCD's L2.
    const int hgroup = ((bx & 7) << 1) | (bx >> 3);
    const int h0 = hgroup * 8;
    const int n = blockIdx.y;
    const int lane = tid & 63;
    const int l16 = lane & 15;
    const int q = lane >> 4;            // 0..3
    const int wav = tid >> 6;           // 0..7
    const int hsel = wav >> 2;          // wave's row within a pair-step
    const int sub = wav & 3;
    const int ok_t = (sub & 1) * 2;     // B-frag tiles ok_t, ok_t+1 (32 ok)
    const int w_base = (sub >> 1) * 64; // wave covers w w_base..+63

    // bias hoisted: per-lane ok values for the two tiles this wave owns
    float bias_r[2];
    #pragma unroll
    for (int mi = 0; mi < 2; ++mi)
        bias_r[mi] = bias[(ok_t + mi) * 16 + l16];

    // halo zeros (wi=0 -> w=-1, wi=129 -> w=128) for all 6 row buffers
    if (tid < 384) {
        int it = tid >> 6;
        int idx = tid & 63;
        int c = idx & 31;
        int wi = (idx < 32) ? 0 : 129;
        lds_x[it * XROW + xel(wi, c)] = 0;
    }

    const int c = (tid >> 5) * 2;            // even channel 0..30
    const int wq = tid & 31;                 // float4 index along w
    const float* xc0 = x + ((size_t)n * CIN + c) * HH * WW;
    const float* xc1 = xc0 + (size_t)HH * WW;

    // ---- upfront stage: input rows h0-1 .. h0+2 -> bufs 0..3 ----
    #pragma unroll
    for (int it = 0; it < 4; ++it) {
        const int r = h0 - 1 + it;
        float4 va = {0.f, 0.f, 0.f, 0.f}, vb = {0.f, 0.f, 0.f, 0.f};
        if ((unsigned)r < HH) {
            va = *((const float4*)(xc0 + (size_t)r * WW) + wq);
            vb = *((const float4*)(xc1 + (size_t)r * WW) + wq);
        }
        unsigned short* lrow = lds_x + it * XROW;
        #pragma unroll
        for (int j = 0; j < 4; ++j) {
            __hip_bfloat162 h2 = __float22bfloat162_rn(
                make_float2((&va.x)[j], (&vb.x)[j]));
            *(unsigned int*)&lrow[xel(wq * 4 + j + 1, c)] = *(unsigned int*)&h2;
        }
    }

    // ---- prefetch rows h0+3, h0+4 into pre[0] (always in-bounds: h0<=120) ----
    float4 pre[2][4];   // [parity][rowA_c, rowA_c+1, rowB_c, rowB_c+1]
    pre[0][0] = *((const float4*)(xc0 + (size_t)(h0 + 3) * WW) + wq);
    pre[0][1] = *((const float4*)(xc1 + (size_t)(h0 + 3) * WW) + wq);
    pre[0][2] = *((const float4*)(xc0 + (size_t)(h0 + 4) * WW) + wq);
    pre[0][3] = *((const float4*)(xc1 + (size_t)(h0 + 4) * WW) + wq);

    __syncthreads();

    // ---- 4 steps; step s computes output rows h0+2s, h0+2s+1 from the ring.
    //      ring buf for input row (h0+rr) is ((rr+1) % 6).
    #pragma unroll
    for (int s = 0; s < 4; ++s) {
        // prefetch the pair consumed two steps ahead; issue before compute so
        // the MFMA phase covers the HBM latency
        if (s < 2) {
            const int r0 = h0 + 2 * s + 5;   // always < 128
            const int r1 = h0 + 2 * s + 6;   // ==128 only when s==1, h0==120
            pre[(s + 1) & 1][0] = *((const float4*)(xc0 + (size_t)r0 * WW) + wq);
            pre[(s + 1) & 1][1] = *((const float4*)(xc1 + (size_t)r0 * WW) + wq);
            if (r1 < HH) {
                pre[(s + 1) & 1][2] = *((const float4*)(xc0 + (size_t)r1 * WW) + wq);
                pre[(s + 1) & 1][3] = *((const float4*)(xc1 + (size_t)r1 * WW) + wq);
            } else {
                pre[(s + 1) & 1][2] = (float4){0.f, 0.f, 0.f, 0.f};
                pre[(s + 1) & 1][3] = (float4){0.f, 0.f, 0.f, 0.f};
            }
        }

        f32x4 acc[2][4];
        #pragma unroll
        for (int mi = 0; mi < 2; ++mi)
            #pragma unroll
            for (int wt = 0; wt < 4; ++wt)
                acc[mi][wt] = (f32x4){0.f, 0.f, 0.f, 0.f};

        #pragma unroll 1
        for (int kr = 0; kr < 3; ++kr) {
            int bi = 2 * s + hsel + kr;      // <= 9
            if (bi >= 6) bi -= 6;
            const unsigned short* lrow = lds_x + bi * XROW;
            #pragma unroll
            for (int kc = 0; kc < 3; ++kc) {
                const int kidx = kr * 3 + kc;
                bf16x8 wf[2];
                #pragma unroll
                for (int mi = 0; mi < 2; ++mi)
                    wf[mi] = *(const bf16x8*)
                        &wfrag[(size_t)(((kidx * 4) + ok_t + mi) * 64 + lane) * 8];
                #pragma unroll
                for (int wt = 0; wt < 4; ++wt) {
                    bf16x8 xf = *(const bf16x8*)
                        &lrow[xel(w_base + wt * 16 + l16 + kc, q * 8)];
                    #pragma unroll
                    for (int mi = 0; mi < 2; ++mi)
                        acc[mi][wt] = __builtin_amdgcn_mfma_f32_16x16x32_bf16(
                            xf, wf[mi], acc[mi][wt], 0, 0, 0);   // A=x, B=w
                }
            }
        }

        if (s < 3) {
            // publish rows h0+2s+3, h0+2s+4 -> bufs (2s+4)%6, (2s+5)%6
            // (not read by step s, read by step s+1)
            unsigned short* lr0 = lds_x + ((2 * s + 4) % 6) * XROW;
            unsigned short* lr1 = lds_x + ((2 * s + 5) % 6) * XROW;
            #pragma unroll
            for (int j = 0; j < 4; ++j) {
                __hip_bfloat162 h2a = __float22bfloat162_rn(
                    make_float2((&pre[s & 1][0].x)[j], (&pre[s & 1][1].x)[j]));
                *(unsigned int*)&lr0[xel(wq * 4 + j + 1, c)] = *(unsigned int*)&h2a;
                __hip_bfloat162 h2b = __float22bfloat162_rn(
                    make_float2((&pre[s & 1][2].x)[j], (&pre[s & 1][3].x)[j]));
                *(unsigned int*)&lr1[xel(wq * 4 + j + 1, c)] = *(unsigned int*)&h2b;
            }
            __syncthreads();
        }

        // ---- epilogue after the barrier: stores overlap step s+1 compute.
        //      D layout (swapped): col=lane&15 -> ok, row=q*4+reg -> w, so
        //      each fragment is one float4 store per lane.
        {
            const int h = h0 + 2 * s + hsel;
            #pragma unroll
            for (int mi = 0; mi < 2; ++mi) {
                const int ok = (ok_t + mi) * 16 + l16;
                const float bv = bias_r[mi];
                float* orow = out + (((size_t)n * NK + ok) * HH + h) * WW;
                #pragma unroll
                for (int wt = 0; wt < 4; ++wt) {
                    f32x4 v = acc[mi][wt];
                    float4 o = make_float4(v[0] + bv, v[1] + bv, v[2] + bv, v[3] + bv);
                    *(float4*)&orow[w_base + wt * 16 + q * 4] = o;
                }
            }
        }
    }
}

extern "C" void kernel_launch(void* const* d_in, const int* in_sizes, int n_in,
                              void* d_out, int out_size, void* d_ws, size_t ws_size,
                              hipStream_t stream) {
    const float* x    = (const float*)d_in[0];
    const float* kern = (const float*)d_in[1];
    const float* bias = (const float*)d_in[2];
    float* out = (float*)d_out;
    unsigned short* wfrag = (unsigned short*)d_ws;   // 18432 bf16 = 36864 B

    repack_w<<<72, 256, 0, stream>>>(kern, wfrag);
    dim3 grid(16, NB);  // (swizzled h-octet, batch)
    conv3x3_mfma<<<grid, 512, 0, stream>>>(x, wfrag, bias, out);
}